// Round 1
// baseline (939.293 us; speedup 1.0000x reference)
//
#include <hip/hip_runtime.h>
#include <math.h>

#define THREADS 256

// ---------------------------------------------------------------------------
// edge_index dtype detection: reference says int64, harness hints int32.
// For int64 little-endian values < 2^32, the odd int32 words are 0.
// P(four int32 edge values all == 0) ~ (1e-5)^4 -> negligible.
// ---------------------------------------------------------------------------
__global__ void detect_i64_kernel(const int* __restrict__ ei32, int* __restrict__ flag) {
    if (threadIdx.x == 0 && blockIdx.x == 0) {
        int z = (ei32[1] == 0) + (ei32[3] == 0) + (ei32[5] == 0) + (ei32[7] == 0);
        *flag = (z == 4) ? 1 : 0;
    }
}

__device__ __forceinline__ int edge_at(const void* ei, int is64, size_t idx) {
    return is64 ? (int)((const long long*)ei)[idx] : ((const int*)ei)[idx];
}

// deg[i] = 1.0 (self-loop weight), cnt[i] = 0
__global__ void init_kernel(float* __restrict__ deg, int* __restrict__ cnt, int N) {
    int i = blockIdx.x * THREADS + threadIdx.x;
    if (i < N) { deg[i] = 1.0f; cnt[i] = 0; }
}

// deg[col] += ew[e]; cnt[col] += 1   (in-degree histogram)
__global__ void edge_deg_kernel(const void* __restrict__ ei, const float* __restrict__ ew,
                                const int* __restrict__ flag,
                                float* __restrict__ deg, int* __restrict__ cnt, int E) {
    int e = blockIdx.x * THREADS + threadIdx.x;
    if (e >= E) return;
    int is64 = *flag;
    int c = edge_at(ei, is64, (size_t)E + e);
    atomicAdd(deg + c, ew[e]);
    atomicAdd(cnt + c, 1);
}

// deg -> deg^{-1/2}  (deg >= 1 always due to self-loop, keep guard anyway)
__global__ void dinv_kernel(float* __restrict__ deg, int N) {
    int i = blockIdx.x * THREADS + threadIdx.x;
    if (i < N) { float d = deg[i]; deg[i] = (d > 0.f) ? rsqrtf(d) : 0.f; }
}

// ---- hierarchical exclusive scan of cnt[0..N) -> colptr -------------------
// K1: per-1024-chunk totals
__global__ void chunk_sum_kernel(const int* __restrict__ cnt, int* __restrict__ partial, int N) {
    int b = blockIdx.x, tid = threadIdx.x;
    int base = b * 1024;
    int v = 0;
#pragma unroll
    for (int k = 0; k < 4; ++k) {
        int i = base + k * 256 + tid;
        if (i < N) v += cnt[i];
    }
#pragma unroll
    for (int m = 32; m >= 1; m >>= 1) v += __shfl_down(v, m);
    __shared__ int wsum[4];
    if ((tid & 63) == 0) wsum[tid >> 6] = v;
    __syncthreads();
    if (tid == 0) partial[b] = wsum[0] + wsum[1] + wsum[2] + wsum[3];
}

// K2: exclusive scan of up to 128 partials (single block); also colptr[N] = E
__global__ void scan_partials_kernel(const int* __restrict__ partial, int* __restrict__ psum,
                                     int* __restrict__ colptr, int NB, int N, int E) {
    __shared__ int sd[128];
    int t = threadIdx.x;
    int v = (t < NB) ? partial[t] : 0;
    sd[t] = v;
    __syncthreads();
    for (int off = 1; off < 128; off <<= 1) {
        int x = (t >= off) ? sd[t - off] : 0;
        __syncthreads();
        sd[t] += x;
        __syncthreads();
    }
    if (t < NB) psum[t] = sd[t] - v;
    if (t == 0) colptr[N] = E;
}

// K3: per-chunk exclusive scan + add chunk base; also re-zero cnt for fill pass
__global__ void chunk_scan_kernel(const int* __restrict__ cnt, const int* __restrict__ psum,
                                  int* __restrict__ colptr, int* __restrict__ cntz, int N) {
    int b = blockIdx.x, tid = threadIdx.x;
    int base = b * 1024 + tid * 4;
    int v0 = 0, v1 = 0, v2 = 0, v3 = 0;
    if (base + 3 < N) {
        int4 v = *(const int4*)(cnt + base);
        v0 = v.x; v1 = v.y; v2 = v.z; v3 = v.w;
    } else {
        if (base + 0 < N) v0 = cnt[base + 0];
        if (base + 1 < N) v1 = cnt[base + 1];
        if (base + 2 < N) v2 = cnt[base + 2];
        if (base + 3 < N) v3 = cnt[base + 3];
    }
    int s0 = v0, s1 = s0 + v1, s2 = s1 + v2, s3 = s2 + v3; // inclusive in-thread
    int tsum = s3;
    int lane = tid & 63;
    int incl = tsum;
#pragma unroll
    for (int off = 1; off < 64; off <<= 1) {
        int x = __shfl_up(incl, off);
        if (lane >= off) incl += x;
    }
    __shared__ int wsum[4];
    if (lane == 63) wsum[tid >> 6] = incl;
    __syncthreads();
    int wbase = 0;
    for (int w = 0; w < (tid >> 6); ++w) wbase += wsum[w];
    int ebase = psum[b] + wbase + (incl - tsum); // exclusive base for this thread's 4
    int o0 = ebase, o1 = ebase + s0, o2 = ebase + s1, o3 = ebase + s2;
    if (base + 3 < N) {
        *(int4*)(colptr + base) = make_int4(o0, o1, o2, o3);
        *(int4*)(cntz + base) = make_int4(0, 0, 0, 0);
    } else {
        if (base + 0 < N) { colptr[base + 0] = o0; cntz[base + 0] = 0; }
        if (base + 1 < N) { colptr[base + 1] = o1; cntz[base + 1] = 0; }
        if (base + 2 < N) { colptr[base + 2] = o2; cntz[base + 2] = 0; }
        if (base + 3 < N) { colptr[base + 3] = o3; cntz[base + 3] = 0; }
    }
}

// scatter edges into CSR-by-destination; norm = dinv[r]*ew*dinv[c]
__global__ void edge_fill_kernel(const void* __restrict__ ei, const float* __restrict__ ew,
                                 const int* __restrict__ flag, const float* __restrict__ dinv,
                                 const int* __restrict__ colptr, int* __restrict__ cnt,
                                 int* __restrict__ esrc, float* __restrict__ enorm, int E) {
    int e = blockIdx.x * THREADS + threadIdx.x;
    if (e >= E) return;
    int is64 = *flag;
    int r = edge_at(ei, is64, (size_t)e);
    int c = edge_at(ei, is64, (size_t)E + e);
    float nrm = dinv[r] * ew[e] * dinv[c];
    int pos = colptr[c] + atomicAdd(cnt + c, 1);
    esrc[pos] = r;
    enorm[pos] = nrm;
}

// Y[N,DOUT] = X[N,64] @ W[64,DOUT]
template <int DOUT>
__global__ void gemm_kernel(const float* __restrict__ X, const float* __restrict__ W,
                            float* __restrict__ Y, int N) {
    constexpr int RPB = 256 / DOUT; // rows per block
    __shared__ float Wl[64 * DOUT];
    __shared__ float Xl[RPB * 64];
    int tid = threadIdx.x;
    for (int i = tid; i < 64 * DOUT; i += 256) Wl[i] = W[i];
    int base = blockIdx.x * RPB;
    for (int i = tid; i < RPB * 64; i += 256) {
        int rr = base + i / 64;
        Xl[i] = (rr < N) ? X[(size_t)rr * 64 + (i & 63)] : 0.f;
    }
    __syncthreads();
    int r = tid / DOUT, c = tid % DOUT;
    int row = base + r;
    if (row < N) {
        float acc = 0.f;
#pragma unroll
        for (int k = 0; k < 64; ++k) acc = fmaf(Xl[r * 64 + k], Wl[k * DOUT + c], acc);
        Y[(size_t)row * DOUT + c] = acc;
    }
}

// layer-1 aggregation: one 64-lane wave per node, lane = feature dim; + bias + ReLU
__global__ void agg1_kernel(const float* __restrict__ X1, const int* __restrict__ colptr,
                            const int* __restrict__ esrc, const float* __restrict__ enorm,
                            const float* __restrict__ dinv, const float* __restrict__ bias,
                            float* __restrict__ H, int N) {
    int tid = threadIdx.x;
    int node = blockIdx.x * 4 + (tid >> 6);
    int d = tid & 63;
    if (node >= N) return;
    float di = dinv[node];
    float acc = bias[d] + di * di * X1[(size_t)node * 64 + d];
    int s = colptr[node], e = colptr[node + 1];
    for (int j = s; j < e; ++j) {
        int r = esrc[j];
        float w = enorm[j];
        acc = fmaf(w, X1[(size_t)r * 64 + d], acc);
    }
    H[(size_t)node * 64 + d] = fmaxf(acc, 0.f);
}

// layer-2 aggregation + bias + row L2-normalize: 32 lanes per node
__global__ void agg2_kernel(const float* __restrict__ X2, const int* __restrict__ colptr,
                            const int* __restrict__ esrc, const float* __restrict__ enorm,
                            const float* __restrict__ dinv, const float* __restrict__ bias,
                            float* __restrict__ out, int N) {
    int tid = threadIdx.x;
    int node = blockIdx.x * 8 + (tid >> 5);
    int d = tid & 31;
    if (node >= N) return;
    float di = dinv[node];
    float acc = bias[d] + di * di * X2[(size_t)node * 32 + d];
    int s = colptr[node], e = colptr[node + 1];
    for (int j = s; j < e; ++j) {
        acc = fmaf(enorm[j], X2[(size_t)esrc[j] * 32 + d], acc);
    }
    float ss = acc * acc;
#pragma unroll
    for (int m = 16; m >= 1; m >>= 1) ss += __shfl_xor(ss, m); // stays in 32-lane half
    float l2 = sqrtf(ss);
    out[(size_t)node * 32 + d] = acc / fmaxf(l2, 1e-12f);
}

extern "C" void kernel_launch(void* const* d_in, const int* in_sizes, int n_in,
                              void* d_out, int out_size, void* d_ws, size_t ws_size,
                              hipStream_t stream) {
    const void* ei = d_in[0];                    // edge_index [2,E] int32 or int64
    const float* ew = (const float*)d_in[1];     // [E]
    const float* emb = (const float*)d_in[2];    // [N,64]
    const float* W1 = (const float*)d_in[3];     // [64,64]
    const float* b1 = (const float*)d_in[4];     // [64]
    const float* W2 = (const float*)d_in[5];     // [64,32]
    const float* b2 = (const float*)d_in[6];     // [32]
    float* outp = (float*)d_out;                 // [N,32]

    int E = in_sizes[0] / 2;
    int N = in_sizes[2] / 64;
    int NB = (N + 1023) / 1024;

    // workspace carve-out (~75 MiB)
    char* p = (char*)d_ws;
    auto alloc = [&](size_t bytes) {
        void* q = (void*)p;
        p += (bytes + 255) & ~(size_t)255;
        return q;
    };
    float* deg     = (float*)alloc((size_t)N * 4);         // degree, then dinv
    int*   cnt     = (int*)alloc((size_t)N * 4);
    int*   colptr  = (int*)alloc(((size_t)N + 1) * 4);
    int*   partial = (int*)alloc((size_t)NB * 4);
    int*   psum    = (int*)alloc((size_t)NB * 4);
    int*   flag    = (int*)alloc(256);
    int*   esrc    = (int*)alloc((size_t)E * 4);
    float* enorm   = (float*)alloc((size_t)E * 4);
    float* bufA    = (float*)alloc((size_t)N * 64 * 4);    // x1, then x2
    float* bufB    = (float*)alloc((size_t)N * 64 * 4);    // h

    int nblkN = (N + THREADS - 1) / THREADS;
    int nblkE = (E + THREADS - 1) / THREADS;

    detect_i64_kernel<<<1, 64, 0, stream>>>((const int*)ei, flag);
    init_kernel<<<nblkN, THREADS, 0, stream>>>(deg, cnt, N);
    edge_deg_kernel<<<nblkE, THREADS, 0, stream>>>(ei, ew, flag, deg, cnt, E);
    dinv_kernel<<<nblkN, THREADS, 0, stream>>>(deg, N);
    chunk_sum_kernel<<<NB, THREADS, 0, stream>>>(cnt, partial, N);
    scan_partials_kernel<<<1, 128, 0, stream>>>(partial, psum, colptr, NB, N, E);
    chunk_scan_kernel<<<NB, THREADS, 0, stream>>>(cnt, psum, colptr, cnt, N);
    edge_fill_kernel<<<nblkE, THREADS, 0, stream>>>(ei, ew, flag, deg, colptr, cnt,
                                                    esrc, enorm, E);
    gemm_kernel<64><<<(N + 3) / 4, THREADS, 0, stream>>>(emb, W1, bufA, N);
    agg1_kernel<<<(N + 3) / 4, THREADS, 0, stream>>>(bufA, colptr, esrc, enorm, deg, b1,
                                                     bufB, N);
    gemm_kernel<32><<<(N + 7) / 8, THREADS, 0, stream>>>(bufB, W2, bufA, N);
    agg2_kernel<<<(N + 7) / 8, THREADS, 0, stream>>>(bufA, colptr, esrc, enorm, deg, b2,
                                                     outp, N);
}

// Round 2
// 805.326 us; speedup vs baseline: 1.1664x; 1.1664x over previous
//
#include <hip/hip_runtime.h>
#include <math.h>

#define THREADS 256

// ---------------------------------------------------------------------------
// edge_index dtype detection: reference says int64, harness may provide int32.
// For int64 little-endian values < 2^32, the odd int32 words are 0.
// ---------------------------------------------------------------------------
__global__ void detect_i64_kernel(const int* __restrict__ ei32, int* __restrict__ flag) {
    if (threadIdx.x == 0 && blockIdx.x == 0) {
        int z = (ei32[1] == 0) + (ei32[3] == 0) + (ei32[5] == 0) + (ei32[7] == 0);
        *flag = (z == 4) ? 1 : 0;
    }
}

__device__ __forceinline__ int edge_at(const void* ei, int is64, size_t idx) {
    return is64 ? (int)((const long long*)ei)[idx] : ((const int*)ei)[idx];
}

// packed[i] = 0
__global__ void zero_packed_kernel(unsigned long long* __restrict__ packed, int N) {
    int i = blockIdx.x * THREADS + threadIdx.x;
    if (i < N) packed[i] = 0ULL;
}

// ONE u64 atomic per edge: high 32 bits accumulate round(ew * 2^24) (fixed-point
// weighted degree), low 32 bits accumulate edge count. Count < 2^31 -> no carry.
__global__ void edge_deg_kernel(const void* __restrict__ ei, const float* __restrict__ ew,
                                const int* __restrict__ flag,
                                unsigned long long* __restrict__ packed, int E) {
    int e = blockIdx.x * THREADS + threadIdx.x;
    if (e >= E) return;
    int is64 = *flag;
    int c = edge_at(ei, is64, (size_t)E + e);
    unsigned long long w = (unsigned long long)(unsigned int)__float2int_rn(ew[e] * 16777216.0f);
    atomicAdd(packed + c, (w << 32) | 1ULL);
}

// unpack: dinv = rsqrt(hi*2^-24 + 1.0), cnt = lo
__global__ void dinv_kernel(const unsigned long long* __restrict__ packed,
                            float* __restrict__ dinv, int* __restrict__ cnt, int N) {
    int i = blockIdx.x * THREADS + threadIdx.x;
    if (i < N) {
        unsigned long long p = packed[i];
        unsigned int hi = (unsigned int)(p >> 32);
        float deg = (float)hi * 5.9604644775390625e-8f + 1.0f; // *2^-24, + self-loop
        dinv[i] = rsqrtf(deg);                                  // deg >= 1 always
        cnt[i] = (int)(p & 0xffffffffULL);
    }
}

// ---- hierarchical exclusive scan of cnt[0..N) -> colptr -------------------
__global__ void chunk_sum_kernel(const int* __restrict__ cnt, int* __restrict__ partial, int N) {
    int b = blockIdx.x, tid = threadIdx.x;
    int base = b * 1024;
    int v = 0;
#pragma unroll
    for (int k = 0; k < 4; ++k) {
        int i = base + k * 256 + tid;
        if (i < N) v += cnt[i];
    }
#pragma unroll
    for (int m = 32; m >= 1; m >>= 1) v += __shfl_down(v, m);
    __shared__ int wsum[4];
    if ((tid & 63) == 0) wsum[tid >> 6] = v;
    __syncthreads();
    if (tid == 0) partial[b] = wsum[0] + wsum[1] + wsum[2] + wsum[3];
}

__global__ void scan_partials_kernel(const int* __restrict__ partial, int* __restrict__ psum,
                                     int* __restrict__ colptr, int NB, int N, int E) {
    __shared__ int sd[128];
    int t = threadIdx.x;
    int v = (t < NB) ? partial[t] : 0;
    sd[t] = v;
    __syncthreads();
    for (int off = 1; off < 128; off <<= 1) {
        int x = (t >= off) ? sd[t - off] : 0;
        __syncthreads();
        sd[t] += x;
        __syncthreads();
    }
    if (t < NB) psum[t] = sd[t] - v;
    if (t == 0) colptr[N] = E;
}

// per-chunk exclusive scan + chunk base; re-zero cnt for the fill pass
__global__ void chunk_scan_kernel(const int* __restrict__ cnt, const int* __restrict__ psum,
                                  int* __restrict__ colptr, int* __restrict__ cntz, int N) {
    int b = blockIdx.x, tid = threadIdx.x;
    int base = b * 1024 + tid * 4;
    int v0 = 0, v1 = 0, v2 = 0, v3 = 0;
    if (base + 3 < N) {
        int4 v = *(const int4*)(cnt + base);
        v0 = v.x; v1 = v.y; v2 = v.z; v3 = v.w;
    } else {
        if (base + 0 < N) v0 = cnt[base + 0];
        if (base + 1 < N) v1 = cnt[base + 1];
        if (base + 2 < N) v2 = cnt[base + 2];
        if (base + 3 < N) v3 = cnt[base + 3];
    }
    int s0 = v0, s1 = s0 + v1, s2 = s1 + v2, s3 = s2 + v3;
    int tsum = s3;
    int lane = tid & 63;
    int incl = tsum;
#pragma unroll
    for (int off = 1; off < 64; off <<= 1) {
        int x = __shfl_up(incl, off);
        if (lane >= off) incl += x;
    }
    __shared__ int wsum[4];
    if (lane == 63) wsum[tid >> 6] = incl;
    __syncthreads();
    int wbase = 0;
    for (int w = 0; w < (tid >> 6); ++w) wbase += wsum[w];
    int ebase = psum[b] + wbase + (incl - tsum);
    int o0 = ebase, o1 = ebase + s0, o2 = ebase + s1, o3 = ebase + s2;
    if (base + 3 < N) {
        *(int4*)(colptr + base) = make_int4(o0, o1, o2, o3);
        *(int4*)(cntz + base) = make_int4(0, 0, 0, 0);
    } else {
        if (base + 0 < N) { colptr[base + 0] = o0; cntz[base + 0] = 0; }
        if (base + 1 < N) { colptr[base + 1] = o1; cntz[base + 1] = 0; }
        if (base + 2 < N) { colptr[base + 2] = o2; cntz[base + 2] = 0; }
        if (base + 3 < N) { colptr[base + 3] = o3; cntz[base + 3] = 0; }
    }
}

// scatter edges into CSR-by-destination; one packed 8B store per edge
__global__ void edge_fill_kernel(const void* __restrict__ ei, const float* __restrict__ ew,
                                 const int* __restrict__ flag, const float* __restrict__ dinv,
                                 const int* __restrict__ colptr, int* __restrict__ cnt,
                                 int2* __restrict__ epack, int E) {
    int e = blockIdx.x * THREADS + threadIdx.x;
    if (e >= E) return;
    int is64 = *flag;
    int r = edge_at(ei, is64, (size_t)e);
    int c = edge_at(ei, is64, (size_t)E + e);
    float nrm = dinv[r] * ew[e] * dinv[c];
    int pos = colptr[c] + atomicAdd(cnt + c, 1);
    epack[pos] = make_int2(r, __float_as_int(nrm));
}

// Y[N,DOUT] = X[N,64] @ W[64,DOUT]
template <int DOUT>
__global__ void gemm_kernel(const float* __restrict__ X, const float* __restrict__ W,
                            float* __restrict__ Y, int N) {
    constexpr int RPB = 256 / DOUT;
    __shared__ float Wl[64 * DOUT];
    __shared__ float Xl[RPB * 64];
    int tid = threadIdx.x;
    for (int i = tid; i < 64 * DOUT; i += 256) Wl[i] = W[i];
    int base = blockIdx.x * RPB;
    for (int i = tid; i < RPB * 64; i += 256) {
        int rr = base + i / 64;
        Xl[i] = (rr < N) ? X[(size_t)rr * 64 + (i & 63)] : 0.f;
    }
    __syncthreads();
    int r = tid / DOUT, c = tid % DOUT;
    int row = base + r;
    if (row < N) {
        float acc = 0.f;
#pragma unroll
        for (int k = 0; k < 64; ++k) acc = fmaf(Xl[r * 64 + k], Wl[k * DOUT + c], acc);
        Y[(size_t)row * DOUT + c] = acc;
    }
}

// layer-1 aggregation: one 64-lane wave per node, lane = feature dim; + bias + ReLU
__global__ void agg1_kernel(const float* __restrict__ X1, const int* __restrict__ colptr,
                            const int2* __restrict__ epack,
                            const float* __restrict__ dinv, const float* __restrict__ bias,
                            float* __restrict__ H, int N) {
    int tid = threadIdx.x;
    int node = blockIdx.x * 4 + (tid >> 6);
    int d = tid & 63;
    if (node >= N) return;
    float di = dinv[node];
    float acc = bias[d] + di * di * X1[(size_t)node * 64 + d];
    int s = colptr[node], e = colptr[node + 1];
    for (int j = s; j < e; ++j) {
        int2 ep = epack[j];
        acc = fmaf(__int_as_float(ep.y), X1[(size_t)ep.x * 64 + d], acc);
    }
    H[(size_t)node * 64 + d] = fmaxf(acc, 0.f);
}

// layer-2 aggregation + bias + row L2-normalize: 32 lanes per node
__global__ void agg2_kernel(const float* __restrict__ X2, const int* __restrict__ colptr,
                            const int2* __restrict__ epack,
                            const float* __restrict__ dinv, const float* __restrict__ bias,
                            float* __restrict__ out, int N) {
    int tid = threadIdx.x;
    int node = blockIdx.x * 8 + (tid >> 5);
    int d = tid & 31;
    if (node >= N) return;
    float di = dinv[node];
    float acc = bias[d] + di * di * X2[(size_t)node * 32 + d];
    int s = colptr[node], e = colptr[node + 1];
    for (int j = s; j < e; ++j) {
        int2 ep = epack[j];
        acc = fmaf(__int_as_float(ep.y), X2[(size_t)ep.x * 32 + d], acc);
    }
    float ss = acc * acc;
#pragma unroll
    for (int m = 16; m >= 1; m >>= 1) ss += __shfl_xor(ss, m);
    float l2 = sqrtf(ss);
    out[(size_t)node * 32 + d] = acc / fmaxf(l2, 1e-12f);
}

extern "C" void kernel_launch(void* const* d_in, const int* in_sizes, int n_in,
                              void* d_out, int out_size, void* d_ws, size_t ws_size,
                              hipStream_t stream) {
    const void* ei = d_in[0];
    const float* ew = (const float*)d_in[1];
    const float* emb = (const float*)d_in[2];
    const float* W1 = (const float*)d_in[3];
    const float* b1 = (const float*)d_in[4];
    const float* W2 = (const float*)d_in[5];
    const float* b2 = (const float*)d_in[6];
    float* outp = (float*)d_out;

    int E = in_sizes[0] / 2;
    int N = in_sizes[2] / 64;
    int NB = (N + 1023) / 1024;

    char* p = (char*)d_ws;
    auto alloc = [&](size_t bytes) {
        void* q = (void*)p;
        p += (bytes + 255) & ~(size_t)255;
        return q;
    };
    unsigned long long* packed = (unsigned long long*)alloc((size_t)N * 8);
    float* dinv    = (float*)alloc((size_t)N * 4);
    int*   cnt     = (int*)alloc((size_t)N * 4);
    int*   colptr  = (int*)alloc(((size_t)N + 1) * 4);
    int*   partial = (int*)alloc((size_t)NB * 4);
    int*   psum    = (int*)alloc((size_t)NB * 4);
    int*   flag    = (int*)alloc(256);
    int2*  epack   = (int2*)alloc((size_t)E * 8);
    float* bufA    = (float*)alloc((size_t)N * 64 * 4);
    float* bufB    = (float*)alloc((size_t)N * 64 * 4);

    int nblkN = (N + THREADS - 1) / THREADS;
    int nblkE = (E + THREADS - 1) / THREADS;

    detect_i64_kernel<<<1, 64, 0, stream>>>((const int*)ei, flag);
    zero_packed_kernel<<<nblkN, THREADS, 0, stream>>>(packed, N);
    edge_deg_kernel<<<nblkE, THREADS, 0, stream>>>(ei, ew, flag, packed, E);
    dinv_kernel<<<nblkN, THREADS, 0, stream>>>(packed, dinv, cnt, N);
    chunk_sum_kernel<<<NB, THREADS, 0, stream>>>(cnt, partial, N);
    scan_partials_kernel<<<1, 128, 0, stream>>>(partial, psum, colptr, NB, N, E);
    chunk_scan_kernel<<<NB, THREADS, 0, stream>>>(cnt, psum, colptr, cnt, N);
    edge_fill_kernel<<<nblkE, THREADS, 0, stream>>>(ei, ew, flag, dinv, colptr, cnt,
                                                    epack, E);
    gemm_kernel<64><<<(N + 3) / 4, THREADS, 0, stream>>>(emb, W1, bufA, N);
    agg1_kernel<<<(N + 3) / 4, THREADS, 0, stream>>>(bufA, colptr, epack, dinv, b1,
                                                     bufB, N);
    gemm_kernel<32><<<(N + 7) / 8, THREADS, 0, stream>>>(bufB, W2, bufA, N);
    agg2_kernel<<<(N + 7) / 8, THREADS, 0, stream>>>(bufA, colptr, epack, dinv, b2,
                                                     outp, N);
}

// Round 3
// 452.482 us; speedup vs baseline: 2.0759x; 1.7798x over previous
//
#include <hip/hip_runtime.h>
#include <hip/hip_fp16.h>
#include <math.h>

#define THREADS 256

// ---------------------------------------------------------------------------
// edge_index dtype detection: int64 little-endian values < 2^32 have zero odd words.
// ---------------------------------------------------------------------------
__global__ void detect_i64_kernel(const int* __restrict__ ei32, int* __restrict__ flag) {
    if (threadIdx.x == 0 && blockIdx.x == 0) {
        int z = (ei32[1] == 0) + (ei32[3] == 0) + (ei32[5] == 0) + (ei32[7] == 0);
        *flag = (z == 4) ? 1 : 0;
    }
}

__device__ __forceinline__ int edge_at(const void* ei, int is64, size_t idx) {
    return is64 ? (int)((const long long*)ei)[idx] : ((const int*)ei)[idx];
}

__global__ void zero_packed_kernel(unsigned long long* __restrict__ packed, int N) {
    int i = blockIdx.x * THREADS + threadIdx.x;
    if (i < N) packed[i] = 0ULL;
}

// ONE u64 atomic per edge; returned old value's low word = this edge's rank
// within its destination bucket (used by fill pass -> no atomics there).
__global__ void edge_deg_kernel(const void* __restrict__ ei, const float* __restrict__ ew,
                                const int* __restrict__ flag,
                                unsigned long long* __restrict__ packed,
                                int* __restrict__ rank, int E) {
    int e = blockIdx.x * THREADS + threadIdx.x;
    if (e >= E) return;
    int is64 = *flag;
    int c = edge_at(ei, is64, (size_t)E + e);
    unsigned long long w = (unsigned long long)(unsigned int)__float2int_rn(ew[e] * 16777216.0f);
    unsigned long long old = atomicAdd(packed + c, (w << 32) | 1ULL);
    rank[e] = (int)(old & 0xffffffffULL);
}

// unpack: dinv = rsqrt(hi*2^-24 + 1.0), cnt = lo
__global__ void dinv_kernel(const unsigned long long* __restrict__ packed,
                            float* __restrict__ dinv, int* __restrict__ cnt, int N) {
    int i = blockIdx.x * THREADS + threadIdx.x;
    if (i < N) {
        unsigned long long p = packed[i];
        unsigned int hi = (unsigned int)(p >> 32);
        float deg = (float)hi * 5.9604644775390625e-8f + 1.0f;
        dinv[i] = rsqrtf(deg);
        cnt[i] = (int)(p & 0xffffffffULL);
    }
}

// ---- hierarchical exclusive scan of cnt[0..N) -> colptr -------------------
__global__ void chunk_sum_kernel(const int* __restrict__ cnt, int* __restrict__ partial, int N) {
    int b = blockIdx.x, tid = threadIdx.x;
    int base = b * 1024;
    int v = 0;
#pragma unroll
    for (int k = 0; k < 4; ++k) {
        int i = base + k * 256 + tid;
        if (i < N) v += cnt[i];
    }
#pragma unroll
    for (int m = 32; m >= 1; m >>= 1) v += __shfl_down(v, m);
    __shared__ int wsum[4];
    if ((tid & 63) == 0) wsum[tid >> 6] = v;
    __syncthreads();
    if (tid == 0) partial[b] = wsum[0] + wsum[1] + wsum[2] + wsum[3];
}

__global__ void scan_partials_kernel(const int* __restrict__ partial, int* __restrict__ psum,
                                     int* __restrict__ colptr, int NB, int N, int E) {
    __shared__ int sd[128];
    int t = threadIdx.x;
    int v = (t < NB) ? partial[t] : 0;
    sd[t] = v;
    __syncthreads();
    for (int off = 1; off < 128; off <<= 1) {
        int x = (t >= off) ? sd[t - off] : 0;
        __syncthreads();
        sd[t] += x;
        __syncthreads();
    }
    if (t < NB) psum[t] = sd[t] - v;
    if (t == 0) colptr[N] = E;
}

__global__ void chunk_scan_kernel(const int* __restrict__ cnt, const int* __restrict__ psum,
                                  int* __restrict__ colptr, int N) {
    int b = blockIdx.x, tid = threadIdx.x;
    int base = b * 1024 + tid * 4;
    int v0 = 0, v1 = 0, v2 = 0, v3 = 0;
    if (base + 3 < N) {
        int4 v = *(const int4*)(cnt + base);
        v0 = v.x; v1 = v.y; v2 = v.z; v3 = v.w;
    } else {
        if (base + 0 < N) v0 = cnt[base + 0];
        if (base + 1 < N) v1 = cnt[base + 1];
        if (base + 2 < N) v2 = cnt[base + 2];
        if (base + 3 < N) v3 = cnt[base + 3];
    }
    int s0 = v0, s1 = s0 + v1, s2 = s1 + v2, s3 = s2 + v3;
    int tsum = s3;
    int lane = tid & 63;
    int incl = tsum;
#pragma unroll
    for (int off = 1; off < 64; off <<= 1) {
        int x = __shfl_up(incl, off);
        if (lane >= off) incl += x;
    }
    __shared__ int wsum[4];
    if (lane == 63) wsum[tid >> 6] = incl;
    __syncthreads();
    int wbase = 0;
    for (int w = 0; w < (tid >> 6); ++w) wbase += wsum[w];
    int ebase = psum[b] + wbase + (incl - tsum);
    int o0 = ebase, o1 = ebase + s0, o2 = ebase + s1, o3 = ebase + s2;
    if (base + 3 < N) {
        *(int4*)(colptr + base) = make_int4(o0, o1, o2, o3);
    } else {
        if (base + 0 < N) colptr[base + 0] = o0;
        if (base + 1 < N) colptr[base + 1] = o1;
        if (base + 2 < N) colptr[base + 2] = o2;
        if (base + 3 < N) colptr[base + 3] = o3;
    }
}

// atomic-free scatter: pos = colptr[c] + rank[e]
__global__ void edge_fill_kernel(const void* __restrict__ ei, const float* __restrict__ ew,
                                 const int* __restrict__ flag, const float* __restrict__ dinv,
                                 const int* __restrict__ colptr, const int* __restrict__ rank,
                                 int2* __restrict__ epack, int E) {
    int e = blockIdx.x * THREADS + threadIdx.x;
    if (e >= E) return;
    int is64 = *flag;
    int r = edge_at(ei, is64, (size_t)e);
    int c = edge_at(ei, is64, (size_t)E + e);
    float nrm = dinv[r] * ew[e] * dinv[c];
    int pos = colptr[c] + rank[e];
    epack[pos] = make_int2(r, __float_as_int(nrm));
}

// Y[N,DOUT] = X[N,64] @ W[64,DOUT], output fp16 (gather array)
template <int DOUT>
__global__ void gemm_kernel(const float* __restrict__ X, const float* __restrict__ W,
                            __half* __restrict__ Y, int N) {
    constexpr int RPB = 256 / DOUT;
    __shared__ float Wl[64 * DOUT];
    __shared__ float Xl[RPB * 64];
    int tid = threadIdx.x;
    for (int i = tid; i < 64 * DOUT; i += 256) Wl[i] = W[i];
    int base = blockIdx.x * RPB;
    for (int i = tid; i < RPB * 64; i += 256) {
        int rr = base + i / 64;
        Xl[i] = (rr < N) ? X[(size_t)rr * 64 + (i & 63)] : 0.f;
    }
    __syncthreads();
    int r = tid / DOUT, c = tid % DOUT;
    int row = base + r;
    if (row < N) {
        float acc = 0.f;
#pragma unroll
        for (int k = 0; k < 64; ++k) acc = fmaf(Xl[r * 64 + k], Wl[k * DOUT + c], acc);
        Y[(size_t)row * DOUT + c] = __float2half(acc);
    }
}

// layer-1 aggregation: one 64-lane wave per node, lane = dim; MLP x8; + bias + ReLU
__global__ void agg1_kernel(const __half* __restrict__ X1, const int* __restrict__ colptr,
                            const int2* __restrict__ epack,
                            const float* __restrict__ dinv, const float* __restrict__ bias,
                            float* __restrict__ H, int N) {
    int tid = threadIdx.x;
    int node = blockIdx.x * 4 + (tid >> 6);
    int d = tid & 63;
    if (node >= N) return;
    float di = dinv[node];
    float acc = bias[d] + di * di * __half2float(X1[(size_t)node * 64 + d]);
    int s = colptr[node], e = colptr[node + 1];
    int j = s;
    for (; j + 8 <= e; j += 8) {
        int2 e0 = epack[j + 0], e1 = epack[j + 1], e2 = epack[j + 2], e3 = epack[j + 3];
        int2 e4 = epack[j + 4], e5 = epack[j + 5], e6 = epack[j + 6], e7 = epack[j + 7];
        float x0 = __half2float(X1[(size_t)e0.x * 64 + d]);
        float x1 = __half2float(X1[(size_t)e1.x * 64 + d]);
        float x2 = __half2float(X1[(size_t)e2.x * 64 + d]);
        float x3 = __half2float(X1[(size_t)e3.x * 64 + d]);
        float x4 = __half2float(X1[(size_t)e4.x * 64 + d]);
        float x5 = __half2float(X1[(size_t)e5.x * 64 + d]);
        float x6 = __half2float(X1[(size_t)e6.x * 64 + d]);
        float x7 = __half2float(X1[(size_t)e7.x * 64 + d]);
        acc = fmaf(__int_as_float(e0.y), x0, acc);
        acc = fmaf(__int_as_float(e1.y), x1, acc);
        acc = fmaf(__int_as_float(e2.y), x2, acc);
        acc = fmaf(__int_as_float(e3.y), x3, acc);
        acc = fmaf(__int_as_float(e4.y), x4, acc);
        acc = fmaf(__int_as_float(e5.y), x5, acc);
        acc = fmaf(__int_as_float(e6.y), x6, acc);
        acc = fmaf(__int_as_float(e7.y), x7, acc);
    }
    for (; j < e; ++j) {
        int2 ep = epack[j];
        acc = fmaf(__int_as_float(ep.y), __half2float(X1[(size_t)ep.x * 64 + d]), acc);
    }
    H[(size_t)node * 64 + d] = fmaxf(acc, 0.f);
}

// layer-2 aggregation + bias + row L2-normalize: 32 lanes per node; MLP x8
__global__ void agg2_kernel(const __half* __restrict__ X2, const int* __restrict__ colptr,
                            const int2* __restrict__ epack,
                            const float* __restrict__ dinv, const float* __restrict__ bias,
                            float* __restrict__ out, int N) {
    int tid = threadIdx.x;
    int node = blockIdx.x * 8 + (tid >> 5);
    int d = tid & 31;
    if (node >= N) return;
    float di = dinv[node];
    float acc = bias[d] + di * di * __half2float(X2[(size_t)node * 32 + d]);
    int s = colptr[node], e = colptr[node + 1];
    int j = s;
    for (; j + 8 <= e; j += 8) {
        int2 e0 = epack[j + 0], e1 = epack[j + 1], e2 = epack[j + 2], e3 = epack[j + 3];
        int2 e4 = epack[j + 4], e5 = epack[j + 5], e6 = epack[j + 6], e7 = epack[j + 7];
        float x0 = __half2float(X2[(size_t)e0.x * 32 + d]);
        float x1 = __half2float(X2[(size_t)e1.x * 32 + d]);
        float x2 = __half2float(X2[(size_t)e2.x * 32 + d]);
        float x3 = __half2float(X2[(size_t)e3.x * 32 + d]);
        float x4 = __half2float(X2[(size_t)e4.x * 32 + d]);
        float x5 = __half2float(X2[(size_t)e5.x * 32 + d]);
        float x6 = __half2float(X2[(size_t)e6.x * 32 + d]);
        float x7 = __half2float(X2[(size_t)e7.x * 32 + d]);
        acc = fmaf(__int_as_float(e0.y), x0, acc);
        acc = fmaf(__int_as_float(e1.y), x1, acc);
        acc = fmaf(__int_as_float(e2.y), x2, acc);
        acc = fmaf(__int_as_float(e3.y), x3, acc);
        acc = fmaf(__int_as_float(e4.y), x4, acc);
        acc = fmaf(__int_as_float(e5.y), x5, acc);
        acc = fmaf(__int_as_float(e6.y), x6, acc);
        acc = fmaf(__int_as_float(e7.y), x7, acc);
    }
    for (; j < e; ++j) {
        int2 ep = epack[j];
        acc = fmaf(__int_as_float(ep.y), __half2float(X2[(size_t)ep.x * 32 + d]), acc);
    }
    float ss = acc * acc;
#pragma unroll
    for (int m = 16; m >= 1; m >>= 1) ss += __shfl_xor(ss, m);
    float l2 = sqrtf(ss);
    out[(size_t)node * 32 + d] = acc / fmaxf(l2, 1e-12f);
}

extern "C" void kernel_launch(void* const* d_in, const int* in_sizes, int n_in,
                              void* d_out, int out_size, void* d_ws, size_t ws_size,
                              hipStream_t stream) {
    const void* ei = d_in[0];
    const float* ew = (const float*)d_in[1];
    const float* emb = (const float*)d_in[2];
    const float* W1 = (const float*)d_in[3];
    const float* b1 = (const float*)d_in[4];
    const float* W2 = (const float*)d_in[5];
    const float* b2 = (const float*)d_in[6];
    float* outp = (float*)d_out;

    int E = in_sizes[0] / 2;
    int N = in_sizes[2] / 64;
    int NB = (N + 1023) / 1024;

    char* p = (char*)d_ws;
    auto alloc = [&](size_t bytes) {
        void* q = (void*)p;
        p += (bytes + 255) & ~(size_t)255;
        return q;
    };
    unsigned long long* packed = (unsigned long long*)alloc((size_t)N * 8);
    float*  dinv    = (float*)alloc((size_t)N * 4);
    int*    cnt     = (int*)alloc((size_t)N * 4);
    int*    colptr  = (int*)alloc(((size_t)N + 1) * 4);
    int*    partial = (int*)alloc((size_t)NB * 4);
    int*    psum    = (int*)alloc((size_t)NB * 4);
    int*    flag    = (int*)alloc(256);
    int*    rank    = (int*)alloc((size_t)E * 4);
    int2*   epack   = (int2*)alloc((size_t)E * 8);
    __half* X1h     = (__half*)alloc((size_t)N * 64 * 2);   // also reused for X2h
    float*  H       = (float*)alloc((size_t)N * 64 * 4);
    __half* X2h     = X1h;  // X1h dead after agg1; gemm2 overwrites with X2

    int nblkN = (N + THREADS - 1) / THREADS;
    int nblkE = (E + THREADS - 1) / THREADS;

    detect_i64_kernel<<<1, 64, 0, stream>>>((const int*)ei, flag);
    zero_packed_kernel<<<nblkN, THREADS, 0, stream>>>(packed, N);
    edge_deg_kernel<<<nblkE, THREADS, 0, stream>>>(ei, ew, flag, packed, rank, E);
    dinv_kernel<<<nblkN, THREADS, 0, stream>>>(packed, dinv, cnt, N);
    chunk_sum_kernel<<<NB, THREADS, 0, stream>>>(cnt, partial, N);
    scan_partials_kernel<<<1, 128, 0, stream>>>(partial, psum, colptr, NB, N, E);
    chunk_scan_kernel<<<NB, THREADS, 0, stream>>>(cnt, psum, colptr, N);
    edge_fill_kernel<<<nblkE, THREADS, 0, stream>>>(ei, ew, flag, dinv, colptr, rank,
                                                    epack, E);
    gemm_kernel<64><<<(N + 3) / 4, THREADS, 0, stream>>>(emb, W1, X1h, N);
    agg1_kernel<<<(N + 3) / 4, THREADS, 0, stream>>>(X1h, colptr, epack, dinv, b1, H, N);
    gemm_kernel<32><<<(N + 7) / 8, THREADS, 0, stream>>>(H, W2, X2h, N);
    agg2_kernel<<<(N + 7) / 8, THREADS, 0, stream>>>(X2h, colptr, epack, dinv, b2,
                                                     outp, N);
}

// Round 4
// 351.572 us; speedup vs baseline: 2.6717x; 1.2870x over previous
//
#include <hip/hip_runtime.h>
#include <hip/hip_fp16.h>
#include <math.h>

#define THREADS 256
#define BWIDTH 512          // nodes per bucket (pow2, shift 9)
#define BSHIFT 9
#define CHUNK 3125          // edges per partition block (<= 3136 LDS stage)

// ---------------------------------------------------------------------------
// int64 detection + zero bucket counters (fused tiny init)
// ---------------------------------------------------------------------------
__global__ void init_kernel(const int* __restrict__ ei32, int* __restrict__ flag,
                            unsigned int* __restrict__ gcnt) {
    int t = threadIdx.x;
    gcnt[t] = 0u;
    if (t == 0) {
        int z = (ei32[1] == 0) + (ei32[3] == 0) + (ei32[5] == 0) + (ei32[7] == 0);
        *flag = (z == 4) ? 1 : 0;
    }
}

__device__ __forceinline__ int edge_at(const void* ei, int is64, size_t idx) {
    return is64 ? (int)((const long long*)ei)[idx] : ((const int*)ei)[idx];
}

// ---------------------------------------------------------------------------
// P1: per-block bucket histogram; flush reserves each block's range per bucket
// ---------------------------------------------------------------------------
__global__ void p1_count_kernel(const void* __restrict__ ei, const int* __restrict__ flag,
                                unsigned int* __restrict__ gcnt, unsigned int* __restrict__ table,
                                int E, int B) {
    __shared__ unsigned int lcnt[256];
    int t = threadIdx.x, b = blockIdx.x;
    lcnt[t] = 0u;
    __syncthreads();
    int is64 = *flag;
    int base = b * CHUNK;
    int end = min(E, base + CHUNK);
    for (int e = base + t; e < end; e += THREADS) {
        int c = edge_at(ei, is64, (size_t)E + e);
        atomicAdd(&lcnt[c >> BSHIFT], 1u);
    }
    __syncthreads();
    if (t < B) table[(size_t)b * 256 + t] = atomicAdd(&gcnt[t], lcnt[t]);
}

// ---------------------------------------------------------------------------
// P2: exclusive scan of gcnt[0..B) -> bstart[0..B], bstart[B] = E
// ---------------------------------------------------------------------------
__global__ void p2_scan_kernel(const unsigned int* __restrict__ gcnt,
                               unsigned int* __restrict__ bstart, int B, int E) {
    int t = threadIdx.x;
    unsigned int v = (t < B) ? gcnt[t] : 0u;
    unsigned int incl = v;
    int lane = t & 63, wid = t >> 6;
#pragma unroll
    for (int off = 1; off < 64; off <<= 1) {
        unsigned int x = __shfl_up(incl, off);
        if (lane >= off) incl += x;
    }
    __shared__ unsigned int ws4[4];
    if (lane == 63) ws4[wid] = incl;
    __syncthreads();
    unsigned int wb = 0;
    for (int w = 0; w < wid; ++w) wb += ws4[w];
    unsigned int excl = wb + incl - v;
    if (t < B) bstart[t] = excl;
    if (t == 0) bstart[B] = (unsigned int)E;
}

// ---------------------------------------------------------------------------
// P3: stage CHUNK edges in LDS, counting-sort by bucket, write coalesced
// bursts into block-reserved contiguous ranges. record = (r | c_local<<17, ew)
// ---------------------------------------------------------------------------
__global__ void p3_scatter_kernel(const void* __restrict__ ei, const float* __restrict__ ew,
                                  const int* __restrict__ flag,
                                  const unsigned int* __restrict__ bstart,
                                  const unsigned int* __restrict__ table,
                                  int2* __restrict__ out, int E, int B) {
    __shared__ int2 stage[CHUNK];
    __shared__ unsigned char lbin[CHUNK];
    __shared__ unsigned short perm[CHUNK];
    __shared__ unsigned int lcnt[256];
    __shared__ unsigned int lstart[256];
    __shared__ unsigned int lcur[256];
    __shared__ int shiftb[256];
    __shared__ unsigned int ws4[4];

    int t = threadIdx.x, b = blockIdx.x;
    lcnt[t] = 0u;
    __syncthreads();
    int is64 = *flag;
    int base = b * CHUNK;
    int end = min(E, base + CHUNK);
    int n = end - base;
    for (int i = t; i < n; i += THREADS) {
        int e = base + i;
        int r = edge_at(ei, is64, (size_t)e);
        int c = edge_at(ei, is64, (size_t)E + e);
        int bin = c >> BSHIFT;
        stage[i] = make_int2(r | ((c & (BWIDTH - 1)) << 17), __float_as_int(ew[e]));
        lbin[i] = (unsigned char)bin;
        atomicAdd(&lcnt[bin], 1u);
    }
    __syncthreads();
    // in-block exclusive scan of lcnt
    unsigned int v = lcnt[t];
    unsigned int incl = v;
    int lane = t & 63, wid = t >> 6;
#pragma unroll
    for (int off = 1; off < 64; off <<= 1) {
        unsigned int x = __shfl_up(incl, off);
        if (lane >= off) incl += x;
    }
    if (lane == 63) ws4[wid] = incl;
    __syncthreads();
    unsigned int wb = 0;
    for (int w = 0; w < wid; ++w) wb += ws4[w];
    unsigned int excl = wb + incl - v;
    lstart[t] = excl;
    lcur[t] = excl;
    shiftb[t] = (t < B) ? ((int)(bstart[t] + table[(size_t)b * 256 + t]) - (int)excl) : 0;
    __syncthreads();
    for (int i = t; i < n; i += THREADS) {
        unsigned int pos = atomicAdd(&lcur[lbin[i]], 1u);
        perm[pos] = (unsigned short)i;
    }
    __syncthreads();
    for (int k = t; k < n; k += THREADS) {
        int i = perm[k];
        int bin = lbin[i];
        out[(size_t)(shiftb[bin] + k)] = stage[i];
    }
}

// ---------------------------------------------------------------------------
// P5: one block per bucket. Stream bucket edges: LDS count + exact fp32 deg,
// in-block scan -> colptr + dinv, then node-sort within bucket -> csr.
// ---------------------------------------------------------------------------
__global__ void p5_bucket_kernel(const int2* __restrict__ bucketed,
                                 const unsigned int* __restrict__ bstart,
                                 float* __restrict__ dinv, int* __restrict__ colptr,
                                 int2* __restrict__ csr, int N, int E) {
    __shared__ unsigned int cnt[BWIDTH];
    __shared__ float deg[BWIDTH];
    __shared__ unsigned int cur[BWIDTH];
    __shared__ unsigned int ws4[4];

    int t = threadIdx.x, b = blockIdx.x;
    cnt[t] = 0u; cnt[t + 256] = 0u;
    deg[t] = 0.f; deg[t + 256] = 0.f;
    __syncthreads();
    unsigned int s = bstart[b], e2 = bstart[b + 1];
    for (unsigned int j = s + t; j < e2; j += THREADS) {
        int2 v = bucketed[j];
        unsigned int cl = ((unsigned int)v.x) >> 17;
        atomicAdd(&cnt[cl], 1u);
        atomicAdd(&deg[cl], __int_as_float(v.y));
    }
    __syncthreads();
    // scan 512 bins, thread t owns bins 2t, 2t+1
    unsigned int a0 = cnt[2 * t], a1 = cnt[2 * t + 1];
    unsigned int sum = a0 + a1;
    unsigned int incl = sum;
    int lane = t & 63, wid = t >> 6;
#pragma unroll
    for (int off = 1; off < 64; off <<= 1) {
        unsigned int x = __shfl_up(incl, off);
        if (lane >= off) incl += x;
    }
    if (lane == 63) ws4[wid] = incl;
    __syncthreads();
    unsigned int wb = 0;
    for (int w = 0; w < wid; ++w) wb += ws4[w];
    unsigned int exclT = wb + incl - sum;
    unsigned int e0 = exclT, e1 = exclT + a0;
    int node0 = b << BSHIFT;
    int n0 = node0 + 2 * t, n1 = n0 + 1;
    if (n0 < N) {
        colptr[n0] = (int)(s + e0);
        dinv[n0] = rsqrtf(deg[2 * t] + 1.0f);       // +1 self-loop
    }
    if (n1 < N) {
        colptr[n1] = (int)(s + e1);
        dinv[n1] = rsqrtf(deg[2 * t + 1] + 1.0f);
    }
    cur[2 * t] = s + e0;
    cur[2 * t + 1] = s + e1;
    __syncthreads();
    for (unsigned int j = s + t; j < e2; j += THREADS) {
        int2 v = bucketed[j];
        unsigned int cl = ((unsigned int)v.x) >> 17;
        unsigned int pos = atomicAdd(&cur[cl], 1u);
        csr[pos] = v;
    }
    if (b == 0 && t == 0) colptr[N] = E;
}

// ---------------------------------------------------------------------------
// GEMM: Y[N,DOUT] = X[N,64] @ W[64,DOUT], fp16 output
// ---------------------------------------------------------------------------
__device__ __forceinline__ float ldf(const float* p, size_t i) { return p[i]; }
__device__ __forceinline__ float ldf(const __half* p, size_t i) { return __half2float(p[i]); }

template <typename TIN, int DOUT>
__global__ void gemm_kernel(const TIN* __restrict__ X, const float* __restrict__ W,
                            __half* __restrict__ Y, int N) {
    constexpr int RPB = 256 / DOUT;
    __shared__ float Wl[64 * DOUT];
    __shared__ float Xl[RPB * 64];
    int tid = threadIdx.x;
    for (int i = tid; i < 64 * DOUT; i += 256) Wl[i] = W[i];
    int base = blockIdx.x * RPB;
    for (int i = tid; i < RPB * 64; i += 256) {
        int rr = base + i / 64;
        Xl[i] = (rr < N) ? ldf(X, (size_t)rr * 64 + (i & 63)) : 0.f;
    }
    __syncthreads();
    int r = tid / DOUT, c = tid % DOUT;
    int row = base + r;
    if (row < N) {
        float acc = 0.f;
#pragma unroll
        for (int k = 0; k < 64; ++k) acc = fmaf(Xl[r * 64 + k], Wl[k * DOUT + c], acc);
        Y[(size_t)row * DOUT + c] = __float2half(acc);
    }
}

// ---------------------------------------------------------------------------
// agg1: wave per node (64 lanes = dims); on-the-fly norm; bias + ReLU -> fp16
// csr record: (r | c_local<<17, ew); r = x & 0x1FFFF
// ---------------------------------------------------------------------------
__global__ void agg1_kernel(const __half* __restrict__ X1, const int* __restrict__ colptr,
                            const int2* __restrict__ csr, const float* __restrict__ dinv,
                            const float* __restrict__ bias, __half* __restrict__ H, int N) {
    int tid = threadIdx.x;
    int node = blockIdx.x * 4 + (tid >> 6);
    int d = tid & 63;
    if (node >= N) return;
    float di = dinv[node];
    float xself = __half2float(X1[(size_t)node * 64 + d]);
    float accE = 0.f;
    int s = colptr[node], e = colptr[node + 1];
    int j = s;
    for (; j + 8 <= e; j += 8) {
        int2 v0 = csr[j + 0], v1 = csr[j + 1], v2 = csr[j + 2], v3 = csr[j + 3];
        int2 v4 = csr[j + 4], v5 = csr[j + 5], v6 = csr[j + 6], v7 = csr[j + 7];
        int r0 = v0.x & 0x1FFFF, r1 = v1.x & 0x1FFFF, r2 = v2.x & 0x1FFFF, r3 = v3.x & 0x1FFFF;
        int r4 = v4.x & 0x1FFFF, r5 = v5.x & 0x1FFFF, r6 = v6.x & 0x1FFFF, r7 = v7.x & 0x1FFFF;
        float w0 = dinv[r0] * __int_as_float(v0.y);
        float w1 = dinv[r1] * __int_as_float(v1.y);
        float w2 = dinv[r2] * __int_as_float(v2.y);
        float w3 = dinv[r3] * __int_as_float(v3.y);
        float w4 = dinv[r4] * __int_as_float(v4.y);
        float w5 = dinv[r5] * __int_as_float(v5.y);
        float w6 = dinv[r6] * __int_as_float(v6.y);
        float w7 = dinv[r7] * __int_as_float(v7.y);
        float x0 = __half2float(X1[(size_t)r0 * 64 + d]);
        float x1 = __half2float(X1[(size_t)r1 * 64 + d]);
        float x2 = __half2float(X1[(size_t)r2 * 64 + d]);
        float x3 = __half2float(X1[(size_t)r3 * 64 + d]);
        float x4 = __half2float(X1[(size_t)r4 * 64 + d]);
        float x5 = __half2float(X1[(size_t)r5 * 64 + d]);
        float x6 = __half2float(X1[(size_t)r6 * 64 + d]);
        float x7 = __half2float(X1[(size_t)r7 * 64 + d]);
        accE = fmaf(w0, x0, accE); accE = fmaf(w1, x1, accE);
        accE = fmaf(w2, x2, accE); accE = fmaf(w3, x3, accE);
        accE = fmaf(w4, x4, accE); accE = fmaf(w5, x5, accE);
        accE = fmaf(w6, x6, accE); accE = fmaf(w7, x7, accE);
    }
    for (; j < e; ++j) {
        int2 v = csr[j];
        int r = v.x & 0x1FFFF;
        accE = fmaf(dinv[r] * __int_as_float(v.y), __half2float(X1[(size_t)r * 64 + d]), accE);
    }
    float acc = bias[d] + di * fmaf(di, xself, accE);
    H[(size_t)node * 64 + d] = __float2half(fmaxf(acc, 0.f));
}

// ---------------------------------------------------------------------------
// agg2: 32 lanes per node; on-the-fly norm; bias + row L2-normalize -> fp32
// ---------------------------------------------------------------------------
__global__ void agg2_kernel(const __half* __restrict__ X2, const int* __restrict__ colptr,
                            const int2* __restrict__ csr, const float* __restrict__ dinv,
                            const float* __restrict__ bias, float* __restrict__ out, int N) {
    int tid = threadIdx.x;
    int node = blockIdx.x * 8 + (tid >> 5);
    int d = tid & 31;
    if (node >= N) return;
    float di = dinv[node];
    float xself = __half2float(X2[(size_t)node * 32 + d]);
    float accE = 0.f;
    int s = colptr[node], e = colptr[node + 1];
    int j = s;
    for (; j + 8 <= e; j += 8) {
        int2 v0 = csr[j + 0], v1 = csr[j + 1], v2 = csr[j + 2], v3 = csr[j + 3];
        int2 v4 = csr[j + 4], v5 = csr[j + 5], v6 = csr[j + 6], v7 = csr[j + 7];
        int r0 = v0.x & 0x1FFFF, r1 = v1.x & 0x1FFFF, r2 = v2.x & 0x1FFFF, r3 = v3.x & 0x1FFFF;
        int r4 = v4.x & 0x1FFFF, r5 = v5.x & 0x1FFFF, r6 = v6.x & 0x1FFFF, r7 = v7.x & 0x1FFFF;
        float w0 = dinv[r0] * __int_as_float(v0.y);
        float w1 = dinv[r1] * __int_as_float(v1.y);
        float w2 = dinv[r2] * __int_as_float(v2.y);
        float w3 = dinv[r3] * __int_as_float(v3.y);
        float w4 = dinv[r4] * __int_as_float(v4.y);
        float w5 = dinv[r5] * __int_as_float(v5.y);
        float w6 = dinv[r6] * __int_as_float(v6.y);
        float w7 = dinv[r7] * __int_as_float(v7.y);
        float x0 = __half2float(X2[(size_t)r0 * 32 + d]);
        float x1 = __half2float(X2[(size_t)r1 * 32 + d]);
        float x2 = __half2float(X2[(size_t)r2 * 32 + d]);
        float x3 = __half2float(X2[(size_t)r3 * 32 + d]);
        float x4 = __half2float(X2[(size_t)r4 * 32 + d]);
        float x5 = __half2float(X2[(size_t)r5 * 32 + d]);
        float x6 = __half2float(X2[(size_t)r6 * 32 + d]);
        float x7 = __half2float(X2[(size_t)r7 * 32 + d]);
        accE = fmaf(w0, x0, accE); accE = fmaf(w1, x1, accE);
        accE = fmaf(w2, x2, accE); accE = fmaf(w3, x3, accE);
        accE = fmaf(w4, x4, accE); accE = fmaf(w5, x5, accE);
        accE = fmaf(w6, x6, accE); accE = fmaf(w7, x7, accE);
    }
    for (; j < e; ++j) {
        int2 v = csr[j];
        int r = v.x & 0x1FFFF;
        accE = fmaf(dinv[r] * __int_as_float(v.y), __half2float(X2[(size_t)r * 32 + d]), accE);
    }
    float acc = bias[d] + di * fmaf(di, xself, accE);
    float ss = acc * acc;
#pragma unroll
    for (int m = 16; m >= 1; m >>= 1) ss += __shfl_xor(ss, m);
    float l2 = sqrtf(ss);
    out[(size_t)node * 32 + d] = acc / fmaxf(l2, 1e-12f);
}

extern "C" void kernel_launch(void* const* d_in, const int* in_sizes, int n_in,
                              void* d_out, int out_size, void* d_ws, size_t ws_size,
                              hipStream_t stream) {
    const void* ei = d_in[0];
    const float* ew = (const float*)d_in[1];
    const float* emb = (const float*)d_in[2];
    const float* W1 = (const float*)d_in[3];
    const float* b1 = (const float*)d_in[4];
    const float* W2 = (const float*)d_in[5];
    const float* b2 = (const float*)d_in[6];
    float* outp = (float*)d_out;

    int E = in_sizes[0] / 2;
    int N = in_sizes[2] / 64;
    int B = (N + BWIDTH - 1) >> BSHIFT;          // buckets (<=256 for N<=128K)
    int GP = (E + CHUNK - 1) / CHUNK;            // partition blocks

    char* p = (char*)d_ws;
    auto alloc = [&](size_t bytes) {
        void* q = (void*)p;
        p += (bytes + 255) & ~(size_t)255;
        return q;
    };
    unsigned int* gcnt   = (unsigned int*)alloc(256 * 4);
    unsigned int* bstart = (unsigned int*)alloc(257 * 4);
    int*          flag   = (int*)alloc(256);
    unsigned int* table  = (unsigned int*)alloc((size_t)GP * 256 * 4);
    int2*   bucketed = (int2*)alloc((size_t)E * 8);
    int2*   csr      = (int2*)alloc((size_t)E * 8);
    float*  dinv     = (float*)alloc((size_t)N * 4);
    int*    colptr   = (int*)alloc(((size_t)N + 1) * 4);
    __half* X1h      = (__half*)alloc((size_t)N * 64 * 2);   // reused as X2h
    __half* H        = (__half*)alloc((size_t)N * 64 * 2);
    __half* X2h      = X1h;

    init_kernel<<<1, 256, 0, stream>>>((const int*)ei, flag, gcnt);
    p1_count_kernel<<<GP, THREADS, 0, stream>>>(ei, flag, gcnt, table, E, B);
    p2_scan_kernel<<<1, 256, 0, stream>>>(gcnt, bstart, B, E);
    p3_scatter_kernel<<<GP, THREADS, 0, stream>>>(ei, ew, flag, bstart, table,
                                                  bucketed, E, B);
    p5_bucket_kernel<<<B, THREADS, 0, stream>>>(bucketed, bstart, dinv, colptr, csr, N, E);
    gemm_kernel<float, 64><<<(N + 3) / 4, THREADS, 0, stream>>>(emb, W1, X1h, N);
    agg1_kernel<<<(N + 3) / 4, THREADS, 0, stream>>>(X1h, colptr, csr, dinv, b1, H, N);
    gemm_kernel<__half, 32><<<(N + 7) / 8, THREADS, 0, stream>>>(H, W2, X2h, N);
    agg2_kernel<<<(N + 7) / 8, THREADS, 0, stream>>>(X2h, colptr, csr, dinv, b2, outp, N);
}

// Round 5
// 327.066 us; speedup vs baseline: 2.8719x; 1.0749x over previous
//
#include <hip/hip_runtime.h>
#include <hip/hip_fp16.h>
#include <math.h>

#define THREADS 256
#define BWIDTH 512          // nodes per bucket (pow2, shift 9)
#define BSHIFT 9
#define CHUNK 3125          // edges per partition block (<= 3136 LDS stage)

// ---------------------------------------------------------------------------
// int64 detection + zero bucket counters
// ---------------------------------------------------------------------------
__global__ void init_kernel(const int* __restrict__ ei32, int* __restrict__ flag,
                            unsigned int* __restrict__ gcnt) {
    int t = threadIdx.x;
    gcnt[t] = 0u;
    if (t == 0) {
        int z = (ei32[1] == 0) + (ei32[3] == 0) + (ei32[5] == 0) + (ei32[7] == 0);
        *flag = (z == 4) ? 1 : 0;
    }
}

__device__ __forceinline__ int edge_at(const void* ei, int is64, size_t idx) {
    return is64 ? (int)((const long long*)ei)[idx] : ((const int*)ei)[idx];
}

// ---------------------------------------------------------------------------
// P1: per-block bucket histogram; flush reserves each block's range per bucket
// ---------------------------------------------------------------------------
__global__ void p1_count_kernel(const void* __restrict__ ei, const int* __restrict__ flag,
                                unsigned int* __restrict__ gcnt, unsigned int* __restrict__ table,
                                int E, int B) {
    __shared__ unsigned int lcnt[256];
    int t = threadIdx.x, b = blockIdx.x;
    lcnt[t] = 0u;
    __syncthreads();
    int is64 = *flag;
    int base = b * CHUNK;
    int end = min(E, base + CHUNK);
    for (int e = base + t; e < end; e += THREADS) {
        int c = edge_at(ei, is64, (size_t)E + e);
        atomicAdd(&lcnt[c >> BSHIFT], 1u);
    }
    __syncthreads();
    if (t < B) table[(size_t)b * 256 + t] = atomicAdd(&gcnt[t], lcnt[t]);
}

// ---------------------------------------------------------------------------
// P2: exclusive scan of gcnt[0..B) -> bstart[0..B], bstart[B] = E
// ---------------------------------------------------------------------------
__global__ void p2_scan_kernel(const unsigned int* __restrict__ gcnt,
                               unsigned int* __restrict__ bstart, int B, int E) {
    int t = threadIdx.x;
    unsigned int v = (t < B) ? gcnt[t] : 0u;
    unsigned int incl = v;
    int lane = t & 63, wid = t >> 6;
#pragma unroll
    for (int off = 1; off < 64; off <<= 1) {
        unsigned int x = __shfl_up(incl, off);
        if (lane >= off) incl += x;
    }
    __shared__ unsigned int ws4[4];
    if (lane == 63) ws4[wid] = incl;
    __syncthreads();
    unsigned int wb = 0;
    for (int w = 0; w < wid; ++w) wb += ws4[w];
    unsigned int excl = wb + incl - v;
    if (t < B) bstart[t] = excl;
    if (t == 0) bstart[B] = (unsigned int)E;
}

// ---------------------------------------------------------------------------
// P3: stage CHUNK edges in LDS, counting-sort by bucket, write coalesced
// bursts into block-reserved contiguous ranges. record = (r | c_local<<17, ew)
// ---------------------------------------------------------------------------
__global__ void p3_scatter_kernel(const void* __restrict__ ei, const float* __restrict__ ew,
                                  const int* __restrict__ flag,
                                  const unsigned int* __restrict__ bstart,
                                  const unsigned int* __restrict__ table,
                                  int2* __restrict__ out, int E, int B) {
    __shared__ int2 stage[CHUNK];
    __shared__ unsigned char lbin[CHUNK];
    __shared__ unsigned short perm[CHUNK];
    __shared__ unsigned int lcnt[256];
    __shared__ unsigned int lcur[256];
    __shared__ int shiftb[256];
    __shared__ unsigned int ws4[4];

    int t = threadIdx.x, b = blockIdx.x;
    lcnt[t] = 0u;
    __syncthreads();
    int is64 = *flag;
    int base = b * CHUNK;
    int end = min(E, base + CHUNK);
    int n = end - base;
    for (int i = t; i < n; i += THREADS) {
        int e = base + i;
        int r = edge_at(ei, is64, (size_t)e);
        int c = edge_at(ei, is64, (size_t)E + e);
        int bin = c >> BSHIFT;
        stage[i] = make_int2(r | ((c & (BWIDTH - 1)) << 17), __float_as_int(ew[e]));
        lbin[i] = (unsigned char)bin;
        atomicAdd(&lcnt[bin], 1u);
    }
    __syncthreads();
    unsigned int v = lcnt[t];
    unsigned int incl = v;
    int lane = t & 63, wid = t >> 6;
#pragma unroll
    for (int off = 1; off < 64; off <<= 1) {
        unsigned int x = __shfl_up(incl, off);
        if (lane >= off) incl += x;
    }
    if (lane == 63) ws4[wid] = incl;
    __syncthreads();
    unsigned int wb = 0;
    for (int w = 0; w < wid; ++w) wb += ws4[w];
    unsigned int excl = wb + incl - v;
    lcur[t] = excl;
    shiftb[t] = (t < B) ? ((int)(bstart[t] + table[(size_t)b * 256 + t]) - (int)excl) : 0;
    __syncthreads();
    for (int i = t; i < n; i += THREADS) {
        unsigned int pos = atomicAdd(&lcur[lbin[i]], 1u);
        perm[pos] = (unsigned short)i;
    }
    __syncthreads();
    for (int k = t; k < n; k += THREADS) {
        int i = perm[k];
        int bin = lbin[i];
        out[(size_t)(shiftb[bin] + k)] = stage[i];
    }
}

// ---------------------------------------------------------------------------
// P5: one block per bucket. LDS count + exact fp32 deg, scan -> colptr + dinv,
// node-sort within bucket -> csr with w = ew * dinv[c] pre-folded.
// ---------------------------------------------------------------------------
__global__ void p5_bucket_kernel(const int2* __restrict__ bucketed,
                                 const unsigned int* __restrict__ bstart,
                                 float* __restrict__ dinv, int* __restrict__ colptr,
                                 int2* __restrict__ csr, int N, int E) {
    __shared__ unsigned int cnt[BWIDTH];
    __shared__ float deg[BWIDTH];       // degree, then reused as dinv
    __shared__ unsigned int cur[BWIDTH];
    __shared__ unsigned int ws4[4];

    int t = threadIdx.x, b = blockIdx.x;
    cnt[t] = 0u; cnt[t + 256] = 0u;
    deg[t] = 0.f; deg[t + 256] = 0.f;
    __syncthreads();
    unsigned int s = bstart[b], e2 = bstart[b + 1];
    for (unsigned int j = s + t; j < e2; j += THREADS) {
        int2 v = bucketed[j];
        unsigned int cl = ((unsigned int)v.x) >> 17;
        atomicAdd(&cnt[cl], 1u);
        atomicAdd(&deg[cl], __int_as_float(v.y));
    }
    __syncthreads();
    unsigned int a0 = cnt[2 * t], a1 = cnt[2 * t + 1];
    unsigned int sum = a0 + a1;
    unsigned int incl = sum;
    int lane = t & 63, wid = t >> 6;
#pragma unroll
    for (int off = 1; off < 64; off <<= 1) {
        unsigned int x = __shfl_up(incl, off);
        if (lane >= off) incl += x;
    }
    if (lane == 63) ws4[wid] = incl;
    __syncthreads();
    unsigned int wb = 0;
    for (int w = 0; w < wid; ++w) wb += ws4[w];
    unsigned int exclT = wb + incl - sum;
    unsigned int e0 = exclT, e1 = exclT + a0;
    int node0 = b << BSHIFT;
    int n0 = node0 + 2 * t, n1 = n0 + 1;
    float d0 = rsqrtf(deg[2 * t] + 1.0f);       // +1 self-loop
    float d1 = rsqrtf(deg[2 * t + 1] + 1.0f);
    if (n0 < N) { colptr[n0] = (int)(s + e0); dinv[n0] = d0; }
    if (n1 < N) { colptr[n1] = (int)(s + e1); dinv[n1] = d1; }
    deg[2 * t] = d0;            // own bins only; visible after next barrier
    deg[2 * t + 1] = d1;
    cur[2 * t] = s + e0;
    cur[2 * t + 1] = s + e1;
    __syncthreads();
    for (unsigned int j = s + t; j < e2; j += THREADS) {
        int2 v = bucketed[j];
        unsigned int cl = ((unsigned int)v.x) >> 17;
        unsigned int pos = atomicAdd(&cur[cl], 1u);
        float w = __int_as_float(v.y) * deg[cl];        // ew * dinv[c]
        csr[pos] = make_int2(v.x, __float_as_int(w));
    }
    if (b == 0 && t == 0) colptr[N] = E;
}

// ---------------------------------------------------------------------------
// GEMM: Y[N,DOUT] = dinv[row] * (X[N,64] @ W[64,DOUT]), fp16 output
// ---------------------------------------------------------------------------
__device__ __forceinline__ float ldf(const float* p, size_t i) { return p[i]; }
__device__ __forceinline__ float ldf(const __half* p, size_t i) { return __half2float(p[i]); }

template <typename TIN, int DOUT>
__global__ void gemm_kernel(const TIN* __restrict__ X, const float* __restrict__ W,
                            const float* __restrict__ dinv, __half* __restrict__ Y, int N) {
    constexpr int RPB = 256 / DOUT;
    __shared__ float Wl[64 * DOUT];
    __shared__ float Xl[RPB * 64];
    int tid = threadIdx.x;
    for (int i = tid; i < 64 * DOUT; i += 256) Wl[i] = W[i];
    int base = blockIdx.x * RPB;
    for (int i = tid; i < RPB * 64; i += 256) {
        int rr = base + i / 64;
        Xl[i] = (rr < N) ? ldf(X, (size_t)rr * 64 + (i & 63)) : 0.f;
    }
    __syncthreads();
    int r = tid / DOUT, c = tid % DOUT;
    int row = base + r;
    if (row < N) {
        float acc = 0.f;
#pragma unroll
        for (int k = 0; k < 64; ++k) acc = fmaf(Xl[r * 64 + k], Wl[k * DOUT + c], acc);
        Y[(size_t)row * DOUT + c] = __float2half(acc * dinv[row]);
    }
}

// ---------------------------------------------------------------------------
// agg1: wave per node; lane = (edge-slot eo in {0,1}, dim-pair dp in [0,32)).
// 2 edges per wave-iter, 16 in flight; inner loop: load, mask, gather, 2 fma.
// csr: (r | c_local<<17, w = ew*dinv[c]); X1 rows pre-scaled by dinv[r].
// ---------------------------------------------------------------------------
__global__ void agg1_kernel(const __half* __restrict__ X1, const int* __restrict__ colptr,
                            const int2* __restrict__ csr, const float* __restrict__ dinv,
                            const float* __restrict__ bias, __half* __restrict__ H, int N) {
    int tid = threadIdx.x;
    int node = blockIdx.x * 4 + (tid >> 6);
    if (node >= N) return;
    int lane = tid & 63;
    int eo = lane >> 5;
    int dp = lane & 31;
    int s = colptr[node], e = colptr[node + 1];
    float acc0 = 0.f, acc1 = 0.f;
    int j = s;
    while (j + 16 <= e) {
        int2 vv[8];
#pragma unroll
        for (int k = 0; k < 8; ++k) vv[k] = csr[j + 2 * k + eo];
        __half2 hh[8];
#pragma unroll
        for (int k = 0; k < 8; ++k) {
            int r = vv[k].x & 0x1FFFF;
            hh[k] = *(const __half2*)(X1 + ((size_t)r << 6) + (dp << 1));
        }
#pragma unroll
        for (int k = 0; k < 8; ++k) {
            float2 x = __half22float2(hh[k]);
            float w = __int_as_float(vv[k].y);
            acc0 = fmaf(w, x.x, acc0);
            acc1 = fmaf(w, x.y, acc1);
        }
        j += 16;
    }
    for (; j < e; j += 2) {
        int jj = j + eo;
        float w = 0.f;
        int r = 0;
        if (jj < e) { int2 v = csr[jj]; r = v.x & 0x1FFFF; w = __int_as_float(v.y); }
        __half2 h = *(const __half2*)(X1 + ((size_t)r << 6) + (dp << 1));
        float2 x = __half22float2(h);
        acc0 = fmaf(w, x.x, acc0);
        acc1 = fmaf(w, x.y, acc1);
    }
    acc0 += __shfl_xor(acc0, 32);
    acc1 += __shfl_xor(acc1, 32);
    if (eo == 0) {
        float di = dinv[node];
        __half2 hs = *(const __half2*)(X1 + ((size_t)node << 6) + (dp << 1));
        float2 xs = __half22float2(hs);
        float a0 = fmaxf(bias[2 * dp + 0] + fmaf(di, xs.x, acc0), 0.f);
        float a1 = fmaxf(bias[2 * dp + 1] + fmaf(di, xs.y, acc1), 0.f);
        *(__half2*)(H + ((size_t)node << 6) + (dp << 1)) = __floats2half2_rn(a0, a1);
    }
}

// ---------------------------------------------------------------------------
// agg2: wave per node; lane = (eo in {0..3}, dp in [0,16)). 4 edges/iter,
// 16 in flight; + bias + row L2-normalize -> fp32 out.
// ---------------------------------------------------------------------------
__global__ void agg2_kernel(const __half* __restrict__ X2, const int* __restrict__ colptr,
                            const int2* __restrict__ csr, const float* __restrict__ dinv,
                            const float* __restrict__ bias, float* __restrict__ out, int N) {
    int tid = threadIdx.x;
    int node = blockIdx.x * 4 + (tid >> 6);
    if (node >= N) return;
    int lane = tid & 63;
    int eo = lane >> 4;
    int dp = lane & 15;
    int s = colptr[node], e = colptr[node + 1];
    float acc0 = 0.f, acc1 = 0.f;
    int j = s;
    while (j + 16 <= e) {
        int2 vv[4];
#pragma unroll
        for (int k = 0; k < 4; ++k) vv[k] = csr[j + 4 * k + eo];
        __half2 hh[4];
#pragma unroll
        for (int k = 0; k < 4; ++k) {
            int r = vv[k].x & 0x1FFFF;
            hh[k] = *(const __half2*)(X2 + ((size_t)r << 5) + (dp << 1));
        }
#pragma unroll
        for (int k = 0; k < 4; ++k) {
            float2 x = __half22float2(hh[k]);
            float w = __int_as_float(vv[k].y);
            acc0 = fmaf(w, x.x, acc0);
            acc1 = fmaf(w, x.y, acc1);
        }
        j += 16;
    }
    for (; j < e; j += 4) {
        int jj = j + eo;
        float w = 0.f;
        int r = 0;
        if (jj < e) { int2 v = csr[jj]; r = v.x & 0x1FFFF; w = __int_as_float(v.y); }
        __half2 h = *(const __half2*)(X2 + ((size_t)r << 5) + (dp << 1));
        float2 x = __half22float2(h);
        acc0 = fmaf(w, x.x, acc0);
        acc1 = fmaf(w, x.y, acc1);
    }
    acc0 += __shfl_xor(acc0, 16);
    acc1 += __shfl_xor(acc1, 16);
    acc0 += __shfl_xor(acc0, 32);
    acc1 += __shfl_xor(acc1, 32);
    float di = dinv[node];
    __half2 hs = *(const __half2*)(X2 + ((size_t)node << 5) + (dp << 1));
    float2 xs = __half22float2(hs);
    float a0 = bias[2 * dp + 0] + fmaf(di, xs.x, acc0);
    float a1 = bias[2 * dp + 1] + fmaf(di, xs.y, acc1);
    float ss = fmaf(a0, a0, a1 * a1);
#pragma unroll
    for (int m = 1; m <= 8; m <<= 1) ss += __shfl_xor(ss, m);   // within 16-lane group
    float inv = 1.f / fmaxf(sqrtf(ss), 1e-12f);
    if (eo == 0) {
        *(float2*)(out + ((size_t)node << 5) + (dp << 1)) = make_float2(a0 * inv, a1 * inv);
    }
}

extern "C" void kernel_launch(void* const* d_in, const int* in_sizes, int n_in,
                              void* d_out, int out_size, void* d_ws, size_t ws_size,
                              hipStream_t stream) {
    const void* ei = d_in[0];
    const float* ew = (const float*)d_in[1];
    const float* emb = (const float*)d_in[2];
    const float* W1 = (const float*)d_in[3];
    const float* b1 = (const float*)d_in[4];
    const float* W2 = (const float*)d_in[5];
    const float* b2 = (const float*)d_in[6];
    float* outp = (float*)d_out;

    int E = in_sizes[0] / 2;
    int N = in_sizes[2] / 64;
    int B = (N + BWIDTH - 1) >> BSHIFT;
    int GP = (E + CHUNK - 1) / CHUNK;

    char* p = (char*)d_ws;
    auto alloc = [&](size_t bytes) {
        void* q = (void*)p;
        p += (bytes + 255) & ~(size_t)255;
        return q;
    };
    unsigned int* gcnt   = (unsigned int*)alloc(256 * 4);
    unsigned int* bstart = (unsigned int*)alloc(257 * 4);
    int*          flag   = (int*)alloc(256);
    unsigned int* table  = (unsigned int*)alloc((size_t)GP * 256 * 4);
    int2*   bucketed = (int2*)alloc((size_t)E * 8);
    int2*   csr      = (int2*)alloc(((size_t)E + 16) * 8);   // +pad for tail overread
    float*  dinv     = (float*)alloc((size_t)N * 4);
    int*    colptr   = (int*)alloc(((size_t)N + 1) * 4);
    __half* X1h      = (__half*)alloc((size_t)N * 64 * 2);   // reused as X2h
    __half* H        = (__half*)alloc((size_t)N * 64 * 2);
    __half* X2h      = X1h;

    init_kernel<<<1, 256, 0, stream>>>((const int*)ei, flag, gcnt);
    p1_count_kernel<<<GP, THREADS, 0, stream>>>(ei, flag, gcnt, table, E, B);
    p2_scan_kernel<<<1, 256, 0, stream>>>(gcnt, bstart, B, E);
    p3_scatter_kernel<<<GP, THREADS, 0, stream>>>(ei, ew, flag, bstart, table,
                                                  bucketed, E, B);
    p5_bucket_kernel<<<B, THREADS, 0, stream>>>(bucketed, bstart, dinv, colptr, csr, N, E);
    gemm_kernel<float, 64><<<(N + 3) / 4, THREADS, 0, stream>>>(emb, W1, dinv, X1h, N);
    agg1_kernel<<<(N + 3) / 4, THREADS, 0, stream>>>(X1h, colptr, csr, dinv, b1, H, N);
    gemm_kernel<__half, 32><<<(N + 7) / 8, THREADS, 0, stream>>>(H, W2, dinv, X2h, N);
    agg2_kernel<<<(N + 3) / 4, THREADS, 0, stream>>>(X2h, colptr, csr, dinv, b2, outp, N);
}